// Round 1
// baseline (215.036 us; speedup 1.0000x reference)
//
#include <hip/hip_runtime.h>
#include <math.h>

#define NODE_D 128
#define HID 16

// ---------------------------------------------------------------------------
// Kernel 1: U = z @ W1[:128], V = z @ W1[128:]   (per-node MLP factorization)
// W1 is [256,16] row-major, staged in LDS; all lanes read the same LDS address
// per step -> broadcast (conflict-free). 2 nodes/thread to amortize LDS reads.
// ---------------------------------------------------------------------------
__global__ __launch_bounds__(256) void uv_precompute_kernel(
    const float* __restrict__ z, const float* __restrict__ W1,
    float* __restrict__ U, float* __restrict__ V, int n_nodes)
{
    __shared__ float W1s[256 * HID];
    const int tid = threadIdx.x;
    #pragma unroll
    for (int i = 0; i < 16; ++i)
        W1s[tid + i * 256] = W1[tid + i * 256];
    __syncthreads();

    const int n0 = blockIdx.x * 512 + tid;
    const int n1 = n0 + 256;
    const bool ok0 = n0 < n_nodes;
    const bool ok1 = n1 < n_nodes;
    const float4* zp0 = (const float4*)(z + (size_t)(ok0 ? n0 : 0) * NODE_D);
    const float4* zp1 = (const float4*)(z + (size_t)(ok1 ? n1 : 0) * NODE_D);

    float u0[HID], v0[HID], u1[HID], v1[HID];
    #pragma unroll
    for (int j = 0; j < HID; ++j) { u0[j]=0.f; v0[j]=0.f; u1[j]=0.f; v1[j]=0.f; }

    #pragma unroll 2
    for (int c = 0; c < NODE_D/4; ++c) {
        float4 za = zp0[c];
        float4 zb = zp1[c];
        const float* wa = &W1s[c * 4 * HID];                 // rows 4c..4c+3, first half
        const float* wb = &W1s[(NODE_D + c * 4) * HID];      // rows 128+4c..,   second half
        #pragma unroll
        for (int j = 0; j < HID; ++j) {
            float wa0 = wa[j], wa1 = wa[HID + j], wa2 = wa[2*HID + j], wa3 = wa[3*HID + j];
            float wb0 = wb[j], wb1 = wb[HID + j], wb2 = wb[2*HID + j], wb3 = wb[3*HID + j];
            u0[j] = fmaf(za.x, wa0, fmaf(za.y, wa1, fmaf(za.z, wa2, fmaf(za.w, wa3, u0[j]))));
            v0[j] = fmaf(za.x, wb0, fmaf(za.y, wb1, fmaf(za.z, wb2, fmaf(za.w, wb3, v0[j]))));
            u1[j] = fmaf(zb.x, wa0, fmaf(zb.y, wa1, fmaf(zb.z, wa2, fmaf(zb.w, wa3, u1[j]))));
            v1[j] = fmaf(zb.x, wb0, fmaf(zb.y, wb1, fmaf(zb.z, wb2, fmaf(zb.w, wb3, v1[j]))));
        }
    }

    if (ok0) {
        float4* up = (float4*)(U + (size_t)n0 * HID);
        float4* vp = (float4*)(V + (size_t)n0 * HID);
        #pragma unroll
        for (int q = 0; q < 4; ++q) {
            up[q] = make_float4(u0[4*q], u0[4*q+1], u0[4*q+2], u0[4*q+3]);
            vp[q] = make_float4(v0[4*q], v0[4*q+1], v0[4*q+2], v0[4*q+3]);
        }
    }
    if (ok1) {
        float4* up = (float4*)(U + (size_t)n1 * HID);
        float4* vp = (float4*)(V + (size_t)n1 * HID);
        #pragma unroll
        for (int q = 0; q < 4; ++q) {
            up[q] = make_float4(u1[4*q], u1[4*q+1], u1[4*q+2], u1[4*q+3]);
            vp[q] = make_float4(v1[4*q], v1[4*q+1], v1[4*q+2], v1[4*q+3]);
        }
    }
}

// ---------------------------------------------------------------------------
// Kernel 2: per-edge. 16 lanes per edge. Lane l loads z[.][4l..4l+3] and
// z[.][64+4l..], accumulates the dot partial, shuffle-reduces within the
// 16-lane group (xor masks 1/2/4/8 never leave the group). Lane j also does
// the 16-wide hidden layer from the precomputed U/V.
// ---------------------------------------------------------------------------
__global__ __launch_bounds__(256) void edge_kernel(
    const float* __restrict__ z, const int* __restrict__ ei,
    const float* __restrict__ U, const float* __restrict__ V,
    const float* __restrict__ b1, const float* __restrict__ W2,
    const float* __restrict__ b2, float* __restrict__ out, int E)
{
    const int gid  = blockIdx.x * blockDim.x + threadIdx.x;
    const int eid  = gid >> 4;
    const int lane = threadIdx.x & 15;
    if (eid >= E) return;

    const int row = ei[eid];
    const int col = ei[E + eid];

    const float4* zr = (const float4*)(z + (size_t)row * NODE_D);
    const float4* zc = (const float4*)(z + (size_t)col * NODE_D);
    float4 a0 = zr[lane], a1 = zr[lane + 16];
    float4 c0 = zc[lane], c1 = zc[lane + 16];

    float p = a0.x*c0.x + a0.y*c0.y + a0.z*c0.z + a0.w*c0.w
            + a1.x*c1.x + a1.y*c1.y + a1.z*c1.z + a1.w*c1.w;
    p += __shfl_xor(p, 1);
    p += __shfl_xor(p, 2);
    p += __shfl_xor(p, 4);
    p += __shfl_xor(p, 8);

    float hu = U[(size_t)row * HID + lane] + V[(size_t)col * HID + lane] + b1[lane];
    float h  = fmaxf(hu, 0.f);
    float t  = h * W2[lane];
    t += __shfl_xor(t, 1);
    t += __shfl_xor(t, 2);
    t += __shfl_xor(t, 4);
    t += __shfl_xor(t, 8);

    if (lane == 0) {
        float x = t + b2[0];
        // numerically stable softplus: max(x,0) + log1p(exp(-|x|))
        float w = fmaxf(x, 0.f) + log1pf(expf(-fabsf(x)));
        out[eid]     = p;
        out[E + eid] = w;
    }
}

extern "C" void kernel_launch(void* const* d_in, const int* in_sizes, int n_in,
                              void* d_out, int out_size, void* d_ws, size_t ws_size,
                              hipStream_t stream) {
    const float* z  = (const float*)d_in[0];
    const int*   ei = (const int*)  d_in[1];
    const float* W1 = (const float*)d_in[2];
    const float* b1 = (const float*)d_in[3];
    const float* W2 = (const float*)d_in[4];
    const float* b2 = (const float*)d_in[5];
    float* out = (float*)d_out;

    const int n_nodes = in_sizes[0] / NODE_D;   // 100000
    const int E       = in_sizes[1] / 2;        // 600000

    float* U = (float*)d_ws;
    float* V = U + (size_t)n_nodes * HID;       // needs 2*N*16*4 = 12.8 MB of ws

    uv_precompute_kernel<<<(n_nodes + 511) / 512, 256, 0, stream>>>(z, W1, U, V, n_nodes);

    const long long threads = (long long)E * 16;
    edge_kernel<<<(unsigned)((threads + 255) / 256), 256, 0, stream>>>(
        z, ei, U, V, b1, W2, b2, out, E);
}

// Round 2
// 207.035 us; speedup vs baseline: 1.0386x; 1.0386x over previous
//
#include <hip/hip_runtime.h>
#include <math.h>

#define NODE_D 128
#define HID 16

// round-to-nearest-even float -> bf16, packed pairwise
__device__ __forceinline__ unsigned pack2bf16(float a, float b) {
    unsigned ua = __float_as_uint(a);
    ua = (ua + 0x7fffu + ((ua >> 16) & 1u)) >> 16;
    unsigned ub = __float_as_uint(b);
    ub = (ub + 0x7fffu + ((ub >> 16) & 1u)) >> 16;
    return ua | (ub << 16);
}

// ---------------------------------------------------------------------------
// Kernel 1: per-node. U = z @ W1[:128] + b1, V = z @ W1[128:].
// One node per thread. W1 addresses are wave-uniform (no threadIdx term) so
// the compiler promotes them to s_load via the scalar cache — no LDS at all.
// Also emits a bf16 copy of z (for the edge dot) when write_zh != 0.
// ---------------------------------------------------------------------------
__global__ __launch_bounds__(256) void precompute_kernel(
    const float* __restrict__ z, const float* __restrict__ W1,
    const float* __restrict__ b1,
    float* __restrict__ U, float* __restrict__ V,
    uint2* __restrict__ zh, int n_nodes, int write_zh)
{
    const int node = blockIdx.x * 256 + threadIdx.x;
    if (node >= n_nodes) return;

    const float4* zp  = (const float4*)(z + (size_t)node * NODE_D);
    uint2*        zhp = zh + (size_t)node * (NODE_D / 4);

    float u[HID], v[HID];
    #pragma unroll
    for (int j = 0; j < HID; ++j) { u[j] = b1[j]; v[j] = 0.f; }

    #pragma unroll 1
    for (int c = 0; c < NODE_D / 4; ++c) {
        float4 za = zp[c];
        if (write_zh) {
            uint2 pk;
            pk.x = pack2bf16(za.x, za.y);
            pk.y = pack2bf16(za.z, za.w);
            zhp[c] = pk;
        }
        const float* wu = W1 + (size_t)c * 4 * HID;        // rows 4c..4c+3
        const float* wv = wu + NODE_D * HID;               // rows 128+4c..
        #pragma unroll
        for (int j = 0; j < HID; ++j) {
            u[j] = fmaf(za.x, wu[j],
                   fmaf(za.y, wu[HID + j],
                   fmaf(za.z, wu[2 * HID + j],
                   fmaf(za.w, wu[3 * HID + j], u[j]))));
            v[j] = fmaf(za.x, wv[j],
                   fmaf(za.y, wv[HID + j],
                   fmaf(za.z, wv[2 * HID + j],
                   fmaf(za.w, wv[3 * HID + j], v[j]))));
        }
    }

    float4* up = (float4*)(U + (size_t)node * HID);
    float4* vp = (float4*)(V + (size_t)node * HID);
    #pragma unroll
    for (int q = 0; q < 4; ++q) {
        up[q] = make_float4(u[4*q], u[4*q+1], u[4*q+2], u[4*q+3]);
        vp[q] = make_float4(v[4*q], v[4*q+1], v[4*q+2], v[4*q+3]);
    }
}

// ---------------------------------------------------------------------------
// Kernel 2 (bf16 dot path): 16 lanes/edge. Lane l loads 8 bf16 (16 B) of
// each row — half the gather bytes of the fp32 path. U/V/softplus in fp32.
// ---------------------------------------------------------------------------
__global__ __launch_bounds__(256) void edge_kernel_bf16(
    const uint4* __restrict__ zh, const int* __restrict__ ei,
    const float* __restrict__ U, const float* __restrict__ V,
    const float* __restrict__ W2, const float* __restrict__ b2,
    float* __restrict__ out, int E)
{
    const int gid  = blockIdx.x * blockDim.x + threadIdx.x;
    const int eid  = gid >> 4;
    const int lane = threadIdx.x & 15;
    if (eid >= E) return;

    const int row = ei[eid];
    const int col = ei[E + eid];

    uint4 ra = zh[(size_t)row * (NODE_D / 8) + lane];
    uint4 rc = zh[(size_t)col * (NODE_D / 8) + lane];

    float p = 0.f;
    {
        const unsigned* au = (const unsigned*)&ra;
        const unsigned* cu = (const unsigned*)&rc;
        #pragma unroll
        for (int q = 0; q < 4; ++q) {
            float alo = __uint_as_float(au[q] << 16);
            float ahi = __uint_as_float(au[q] & 0xffff0000u);
            float clo = __uint_as_float(cu[q] << 16);
            float chi = __uint_as_float(cu[q] & 0xffff0000u);
            p = fmaf(alo, clo, p);
            p = fmaf(ahi, chi, p);
        }
    }
    p += __shfl_xor(p, 1);
    p += __shfl_xor(p, 2);
    p += __shfl_xor(p, 4);
    p += __shfl_xor(p, 8);

    float hu = U[(size_t)row * HID + lane] + V[(size_t)col * HID + lane];
    float t  = fmaxf(hu, 0.f) * W2[lane];
    t += __shfl_xor(t, 1);
    t += __shfl_xor(t, 2);
    t += __shfl_xor(t, 4);
    t += __shfl_xor(t, 8);

    if (lane == 0) {
        float x = t + b2[0];
        float w = fmaxf(x, 0.f) + log1pf(expf(-fabsf(x)));
        out[eid]     = p;
        out[E + eid] = w;
    }
}

// ---------------------------------------------------------------------------
// Kernel 2 (fp32 fallback, used only if d_ws can't hold the bf16 z copy)
// ---------------------------------------------------------------------------
__global__ __launch_bounds__(256) void edge_kernel_f32(
    const float* __restrict__ z, const int* __restrict__ ei,
    const float* __restrict__ U, const float* __restrict__ V,
    const float* __restrict__ W2, const float* __restrict__ b2,
    float* __restrict__ out, int E)
{
    const int gid  = blockIdx.x * blockDim.x + threadIdx.x;
    const int eid  = gid >> 4;
    const int lane = threadIdx.x & 15;
    if (eid >= E) return;

    const int row = ei[eid];
    const int col = ei[E + eid];

    const float4* zr = (const float4*)(z + (size_t)row * NODE_D);
    const float4* zc = (const float4*)(z + (size_t)col * NODE_D);
    float4 a0 = zr[lane], a1 = zr[lane + 16];
    float4 c0 = zc[lane], c1 = zc[lane + 16];

    float p = a0.x*c0.x + a0.y*c0.y + a0.z*c0.z + a0.w*c0.w
            + a1.x*c1.x + a1.y*c1.y + a1.z*c1.z + a1.w*c1.w;
    p += __shfl_xor(p, 1);
    p += __shfl_xor(p, 2);
    p += __shfl_xor(p, 4);
    p += __shfl_xor(p, 8);

    float hu = U[(size_t)row * HID + lane] + V[(size_t)col * HID + lane];
    float t  = fmaxf(hu, 0.f) * W2[lane];
    t += __shfl_xor(t, 1);
    t += __shfl_xor(t, 2);
    t += __shfl_xor(t, 4);
    t += __shfl_xor(t, 8);

    if (lane == 0) {
        float x = t + b2[0];
        float w = fmaxf(x, 0.f) + log1pf(expf(-fabsf(x)));
        out[eid]     = p;
        out[E + eid] = w;
    }
}

extern "C" void kernel_launch(void* const* d_in, const int* in_sizes, int n_in,
                              void* d_out, int out_size, void* d_ws, size_t ws_size,
                              hipStream_t stream) {
    const float* z  = (const float*)d_in[0];
    const int*   ei = (const int*)  d_in[1];
    const float* W1 = (const float*)d_in[2];
    const float* b1 = (const float*)d_in[3];
    const float* W2 = (const float*)d_in[4];
    const float* b2 = (const float*)d_in[5];
    float* out = (float*)d_out;

    const int n_nodes = in_sizes[0] / NODE_D;   // 100000
    const int E       = in_sizes[1] / 2;        // 600000

    const size_t needUV = (size_t)2 * n_nodes * HID * sizeof(float);  // 12.8 MB
    const size_t needZh = (size_t)n_nodes * NODE_D * 2;               // 25.6 MB
    const int use_bf16  = (ws_size >= needUV + needZh);

    float* U  = (float*)d_ws;
    float* V  = U + (size_t)n_nodes * HID;
    uint2* zh = (uint2*)((char*)d_ws + needUV);

    precompute_kernel<<<(n_nodes + 255) / 256, 256, 0, stream>>>(
        z, W1, b1, U, V, zh, n_nodes, use_bf16);

    const long long threads = (long long)E * 16;
    const unsigned  eblocks = (unsigned)((threads + 255) / 256);
    if (use_bf16) {
        edge_kernel_bf16<<<eblocks, 256, 0, stream>>>(
            (const uint4*)zh, ei, U, V, W2, b2, out, E);
    } else {
        edge_kernel_f32<<<eblocks, 256, 0, stream>>>(
            z, ei, U, V, W2, b2, out, E);
    }
}